// Round 11
// baseline (44.286 us; speedup 1.0000x reference)
//
#include <hip/hip_runtime.h>

#define NN    2048      // number of notes
#define SEGL  32768     // max note length
#define NH    8         // harmonics
#define DURS  4194304   // output duration samples
#define BLK   64                // one wave per block
#define S     16                // consecutive samples per thread
#define TILE  (BLK * S)         // 1024
#define MAXC  64                // staged candidates per chunk (expected ~16)

// accurate sincos (|x| < 2^18): Cody-Waite mod pi + deg-7/deg-8 Taylor,
// (-1)^k applied to both via xor. For |x| < pi/2 it reduces to the raw polys.
__device__ __forceinline__ void sincos_acc(float x, float& s_out, float& c_out) {
    const float kq = rintf(x * 0.31830988618379067f);
    float r = fmaf(kq, -0x1.921FB6p+1f, x);     // pi_hi = fp32(pi), exact in fma
    r = fmaf(kq, 8.7422777e-8f, r);             // -(pi - pi_hi)
    const unsigned sgn = ((unsigned)(int)kq) << 31;
    const float y = r * r;
    float sp = fmaf(y, -1.9841270e-4f, 8.3333333e-3f);
    sp = fmaf(y, sp, -1.6666667e-1f);
    float s = fmaf(r * y, sp, r);
    float cp = fmaf(y, 2.4801587e-5f, -1.3888889e-3f);
    cp = fmaf(y, cp, 4.1666668e-2f);
    cp = fmaf(y, cp, -0.5f);
    float c = fmaf(y, cp, 1.0f);
    s_out = __uint_as_float(__float_as_uint(s) ^ sgn);
    c_out = __uint_as_float(__float_as_uint(c) ^ sgn);
}

__global__ __launch_bounds__(BLK) void synth_gather(
    const float* __restrict__ freq,
    const float* __restrict__ amps,
    const float* __restrict__ gainp,
    const int*  __restrict__ starts,
    const int*  __restrict__ lens,
    float* __restrict__ out)
{
    __shared__ float4 s_c0[MAXC];   // {freq, start(bits), len(bits), -}
    __shared__ float2 s_c1[MAXC];   // {sin(freq), cos(freq)} per candidate

    const int tile_lo = (int)blockIdx.x * TILE;
    const int tile_hi = tile_lo + TILE;

    // Candidate notes = contiguous range [j0, j1) in the sorted start array.
    int lo = 0, hi = NN;
    const int v0 = tile_lo - SEGL;
    while (lo < hi) { int m = (lo + hi) >> 1; if (starts[m] > v0) hi = m; else lo = m + 1; }
    const int j0 = lo;
    lo = 0; hi = NN;
    while (lo < hi) { int m = (lo + hi) >> 1; if (starts[m] >= tile_hi) hi = m; else lo = m + 1; }
    const int j1 = lo;

    // Chebyshev-U basis combination of amps, pre-scaled by 2*g*log2(e),
    // rebased for Horner-in-cos: bt_k = b_k * 2^k.
    const float a0 = amps[0], a1 = amps[1], a2 = amps[2], a3 = amps[3];
    const float a4 = amps[4], a5 = amps[5], a6 = amps[6], a7 = amps[7];
    const float kg = gainp[0] * 2.8853900817779268f;   // 2*log2(e)
    const float bt7 = kg * a7 * 128.0f;
    const float bt6 = kg * a6 * 64.0f;
    const float bt5 = kg * (a5 - 6.0f * a7) * 32.0f;
    const float bt4 = kg * (a4 - 5.0f * a6) * 16.0f;
    const float bt3 = kg * (a3 - 4.0f * a5 + 10.0f * a7) * 8.0f;
    const float bt2 = kg * (a2 - 3.0f * a4 + 6.0f * a6) * 4.0f;
    const float bt1 = kg * (a1 - 2.0f * a3 + 3.0f * a5 - 4.0f * a7) * 2.0f;
    const float bt0 = kg * (a0 - a2 + a4 - a6);

    float acc[S];
#pragma unroll
    for (int i = 0; i < S; ++i) acc[i] = 0.0f;

    const int base = tile_lo + (int)threadIdx.x * S;

    for (int jb = j0; jb < j1; jb += MAXC) {
        const int cchunk = min(j1 - jb, MAXC);
        __syncthreads();
        for (int c = (int)threadIdx.x; c < cchunk; c += BLK) {
            int j = jb + c;
            const float fr = freq[j];
            int st = starts[j];
            int ln = lens[j];
            int rem = DURS - st;          // out_len = min(start+len, dur) - start
            if (rem < 0) rem = 0;
            if (ln > rem) ln = rem;
            if (ln < 0) ln = 0;
            float4 v;
            v.x = fr;
            v.y = __int_as_float(st);
            v.z = __int_as_float(ln);
            v.w = 0.0f;
            s_c0[c] = v;
            float sd, cd;                 // per-candidate rotation constants
            sincos_acc(fr, sd, cd);       // fr in [0,1): kq==0 path
            s_c1[c] = make_float2(sd, cd);
        }
        __syncthreads();

        // software-pipelined candidate loop: prefetch c+1 while processing c
        float4 v_cur = s_c0[0];
        float2 w_cur = s_c1[0];
        for (int c = 0; c < cchunk; ++c) {
            const float4 v = v_cur;
            const float2 w = w_cur;
            if (c + 1 < cchunk) {         // prefetch next candidate's metadata
                v_cur = s_c0[c + 1];
                w_cur = s_c1[c + 1];
            }
            const float fr = v.x;
            const int st = __float_as_int(v.y);
            const int ln = __float_as_int(v.z);
            const int t0 = base - st;
            // this thread's run [t0, t0+S) vs valid [0, ln)
            if (t0 >= ln || t0 + (S - 1) < 0) continue;
            const float sd = w.x;
            const float cd = w.y;

            // anchor phase at this thread's first sample (reference-rounded arg)
            const float ph0 = fr * (float)t0;
            float s, cc;
            sincos_acc(ph0, s, cc);

            if (t0 >= 0 && t0 + S <= ln) {
                // full-cover fast path: no per-sample validity checks
#pragma unroll
                for (int i = 0; i < S; ++i) {
                    float q = fmaf(cc, bt7, bt6);
                    q = fmaf(cc, q, bt5);
                    q = fmaf(cc, q, bt4);
                    q = fmaf(cc, q, bt3);
                    q = fmaf(cc, q, bt2);
                    q = fmaf(cc, q, bt1);
                    q = fmaf(cc, q, bt0);
                    const float e = __builtin_amdgcn_exp2f(s * q);
                    const float rc = __builtin_amdgcn_rcpf(e + 1.0f);
                    acc[i] += fmaf(-2.0f, rc, 1.0f);
                    if (i < S - 1) {                         // last step DCE'd
                        const float sn = fmaf(cc, sd, s * cd);
                        cc = fmaf(-s, sd, cc * cd);
                        s = sn;
                    }
                }
            } else {
                // boundary path: per-sample mask
#pragma unroll
                for (int i = 0; i < S; ++i) {
                    float q = fmaf(cc, bt7, bt6);
                    q = fmaf(cc, q, bt5);
                    q = fmaf(cc, q, bt4);
                    q = fmaf(cc, q, bt3);
                    q = fmaf(cc, q, bt2);
                    q = fmaf(cc, q, bt1);
                    q = fmaf(cc, q, bt0);
                    const float e = __builtin_amdgcn_exp2f(s * q);
                    const float rc = __builtin_amdgcn_rcpf(e + 1.0f);
                    const float term = fmaf(-2.0f, rc, 1.0f);
                    const bool valid = (unsigned)(t0 + i) < (unsigned)ln;
                    acc[i] += valid ? term : 0.0f;
                    if (i < S - 1) {
                        const float sn = fmaf(cc, sd, s * cd);
                        cc = fmaf(-s, sd, cc * cd);
                        s = sn;
                    }
                }
            }
        }
    }

#pragma unroll
    for (int i = 0; i < S; i += 4) {
        float4 o;
        o.x = acc[i]; o.y = acc[i + 1]; o.z = acc[i + 2]; o.w = acc[i + 3];
        *reinterpret_cast<float4*>(&out[base + i]) = o;
    }
}

extern "C" void kernel_launch(void* const* d_in, const int* in_sizes, int n_in,
                              void* d_out, int out_size, void* d_ws, size_t ws_size,
                              hipStream_t stream) {
    const float* freq   = (const float*)d_in[0];
    const float* amps   = (const float*)d_in[1];
    const float* gain   = (const float*)d_in[2];
    const int*   starts = (const int*)d_in[3];
    const int*   lens   = (const int*)d_in[4];
    float* out = (float*)d_out;

    const int grid = DURS / TILE;   // 4096 single-wave blocks
    synth_gather<<<grid, BLK, 0, stream>>>(freq, amps, gain, starts, lens, out);
}

// Round 12
// 33.252 us; speedup vs baseline: 1.3318x; 1.3318x over previous
//
#include <hip/hip_runtime.h>

#define NN    2048      // number of notes
#define SEGL  32768     // max note length
#define NH    8         // harmonics
#define DURS  4194304   // output duration samples
#define BLK   256               // 4-wave blocks: full workgroup-slot occupancy
#define S     4                 // consecutive samples per thread
#define TILE  (BLK * S)         // 1024
#define MAXC  64                // staged candidates per chunk (expected ~16)

// accurate sincos (|x| < 2^18): Cody-Waite mod pi + deg-7/deg-8 Taylor,
// (-1)^k applied to both via xor. For |x| < pi/2 it reduces to the raw polys.
__device__ __forceinline__ void sincos_acc(float x, float& s_out, float& c_out) {
    const float kq = rintf(x * 0.31830988618379067f);
    float r = fmaf(kq, -0x1.921FB6p+1f, x);     // pi_hi = fp32(pi), exact in fma
    r = fmaf(kq, 8.7422777e-8f, r);             // -(pi - pi_hi)
    const unsigned sgn = ((unsigned)(int)kq) << 31;
    const float y = r * r;
    float sp = fmaf(y, -1.9841270e-4f, 8.3333333e-3f);
    sp = fmaf(y, sp, -1.6666667e-1f);
    float s = fmaf(r * y, sp, r);
    float cp = fmaf(y, 2.4801587e-5f, -1.3888889e-3f);
    cp = fmaf(y, cp, 4.1666668e-2f);
    cp = fmaf(y, cp, -0.5f);
    float c = fmaf(y, cp, 1.0f);
    s_out = __uint_as_float(__float_as_uint(s) ^ sgn);
    c_out = __uint_as_float(__float_as_uint(c) ^ sgn);
}

__global__ __launch_bounds__(BLK) void synth_gather(
    const float* __restrict__ freq,
    const float* __restrict__ amps,
    const float* __restrict__ gainp,
    const int*  __restrict__ starts,
    const int*  __restrict__ lens,
    float* __restrict__ out)
{
    __shared__ float4 s_c0[MAXC];   // {freq, start(bits), len(bits), -}
    __shared__ float2 s_c1[MAXC];   // {sin(freq), cos(freq)} per candidate

    const int tile_lo = (int)blockIdx.x * TILE;
    const int tile_hi = tile_lo + TILE;

    // Candidate notes = contiguous range [j0, j1) in the sorted start array.
    int lo = 0, hi = NN;
    const int v0 = tile_lo - SEGL;
    while (lo < hi) { int m = (lo + hi) >> 1; if (starts[m] > v0) hi = m; else lo = m + 1; }
    const int j0 = lo;
    lo = 0; hi = NN;
    while (lo < hi) { int m = (lo + hi) >> 1; if (starts[m] >= tile_hi) hi = m; else lo = m + 1; }
    const int j1 = lo;

    // Chebyshev-U basis combination of amps, pre-scaled by 2*g*log2(e),
    // rebased for Horner-in-cos: bt_k = b_k * 2^k.
    const float a0 = amps[0], a1 = amps[1], a2 = amps[2], a3 = amps[3];
    const float a4 = amps[4], a5 = amps[5], a6 = amps[6], a7 = amps[7];
    const float kg = gainp[0] * 2.8853900817779268f;   // 2*log2(e)
    const float bt7 = kg * a7 * 128.0f;
    const float bt6 = kg * a6 * 64.0f;
    const float bt5 = kg * (a5 - 6.0f * a7) * 32.0f;
    const float bt4 = kg * (a4 - 5.0f * a6) * 16.0f;
    const float bt3 = kg * (a3 - 4.0f * a5 + 10.0f * a7) * 8.0f;
    const float bt2 = kg * (a2 - 3.0f * a4 + 6.0f * a6) * 4.0f;
    const float bt1 = kg * (a1 - 2.0f * a3 + 3.0f * a5 - 4.0f * a7) * 2.0f;
    const float bt0 = kg * (a0 - a2 + a4 - a6);

    float acc[S];
#pragma unroll
    for (int i = 0; i < S; ++i) acc[i] = 0.0f;

    const int base = tile_lo + (int)threadIdx.x * S;

    for (int jb = j0; jb < j1; jb += MAXC) {
        const int cchunk = min(j1 - jb, MAXC);
        __syncthreads();
        for (int c = (int)threadIdx.x; c < cchunk; c += BLK) {
            int j = jb + c;
            const float fr = freq[j];
            int st = starts[j];
            int ln = lens[j];
            int rem = DURS - st;          // out_len = min(start+len, dur) - start
            if (rem < 0) rem = 0;
            if (ln > rem) ln = rem;
            if (ln < 0) ln = 0;
            float4 v;
            v.x = fr;
            v.y = __int_as_float(st);
            v.z = __int_as_float(ln);
            v.w = 0.0f;
            s_c0[c] = v;
            float sd, cd;                 // per-candidate rotation constants
            sincos_acc(fr, sd, cd);       // fr in [0,1): kq==0 path
            s_c1[c] = make_float2(sd, cd);
        }
        __syncthreads();

        for (int c = 0; c < cchunk; ++c) {
            const float4 v = s_c0[c];
            const float fr = v.x;
            const int st = __float_as_int(v.y);
            const int ln = __float_as_int(v.z);
            const int t0 = base - st;
            // this thread's run [t0, t0+S) vs valid [0, ln)
            if (t0 >= ln || t0 + (S - 1) < 0) continue;
            const float2 w = s_c1[c];
            const float sd = w.x;
            const float cd = w.y;

            // anchor phase at this thread's first sample (reference-rounded arg)
            const float ph0 = fr * (float)t0;
            float s, cc;
            sincos_acc(ph0, s, cc);

            if (t0 >= 0 && t0 + S <= ln) {
                // full-cover fast path: no per-sample validity checks
#pragma unroll
                for (int i = 0; i < S; ++i) {
                    float q = fmaf(cc, bt7, bt6);
                    q = fmaf(cc, q, bt5);
                    q = fmaf(cc, q, bt4);
                    q = fmaf(cc, q, bt3);
                    q = fmaf(cc, q, bt2);
                    q = fmaf(cc, q, bt1);
                    q = fmaf(cc, q, bt0);
                    const float e = __builtin_amdgcn_exp2f(s * q);
                    const float rc = __builtin_amdgcn_rcpf(e + 1.0f);
                    acc[i] += fmaf(-2.0f, rc, 1.0f);
                    if (i < S - 1) {                         // last step DCE'd
                        const float sn = fmaf(cc, sd, s * cd);
                        cc = fmaf(-s, sd, cc * cd);
                        s = sn;
                    }
                }
            } else {
                // boundary path: per-sample mask
#pragma unroll
                for (int i = 0; i < S; ++i) {
                    float q = fmaf(cc, bt7, bt6);
                    q = fmaf(cc, q, bt5);
                    q = fmaf(cc, q, bt4);
                    q = fmaf(cc, q, bt3);
                    q = fmaf(cc, q, bt2);
                    q = fmaf(cc, q, bt1);
                    q = fmaf(cc, q, bt0);
                    const float e = __builtin_amdgcn_exp2f(s * q);
                    const float rc = __builtin_amdgcn_rcpf(e + 1.0f);
                    const float term = fmaf(-2.0f, rc, 1.0f);
                    const bool valid = (unsigned)(t0 + i) < (unsigned)ln;
                    acc[i] += valid ? term : 0.0f;
                    if (i < S - 1) {
                        const float sn = fmaf(cc, sd, s * cd);
                        cc = fmaf(-s, sd, cc * cd);
                        s = sn;
                    }
                }
            }
        }
    }

    // coalesced writeout: one float4 per thread (consecutive 16B per lane)
    {
        float4 o;
        o.x = acc[0]; o.y = acc[1]; o.z = acc[2]; o.w = acc[3];
        *reinterpret_cast<float4*>(&out[base]) = o;
    }
}

extern "C" void kernel_launch(void* const* d_in, const int* in_sizes, int n_in,
                              void* d_out, int out_size, void* d_ws, size_t ws_size,
                              hipStream_t stream) {
    const float* freq   = (const float*)d_in[0];
    const float* amps   = (const float*)d_in[1];
    const float* gain   = (const float*)d_in[2];
    const int*   starts = (const int*)d_in[3];
    const int*   lens   = (const int*)d_in[4];
    float* out = (float*)d_out;

    const int grid = DURS / TILE;   // 4096 blocks -> 16/CU, 8 co-resident
    synth_gather<<<grid, BLK, 0, stream>>>(freq, amps, gain, starts, lens, out);
}

// Round 13
// 31.994 us; speedup vs baseline: 1.3842x; 1.0393x over previous
//
#include <hip/hip_runtime.h>

#define NN    2048      // number of notes
#define SEGL  32768     // max note length
#define NH    8         // harmonics
#define DURS  4194304   // output duration samples
#define BLK   256               // 4-wave blocks
#define S     4                 // consecutive samples per thread
#define TILE  (BLK * S)         // 1024
#define MAXC  64                // staged candidates per chunk (one wave stages)

// anchor sincos (0 <= x < 2^18): magic-number RNE reduction mod pi +
// deg-7/deg-8 Taylor; (-1)^k applied to both via xor (parity from magic bits).
__device__ __forceinline__ void sincos_mag(float x, float& s_out, float& c_out) {
    const float MAGIC = 12582912.0f;                  // 1.5*2^23
    const float kf = fmaf(x, 0.31830988618379067f, MAGIC);
    const unsigned sgn = __float_as_uint(kf) << 31;   // mantissa bit0 = parity(k)
    const float kq = kf - MAGIC;                      // k as float (RNE)
    float r = fmaf(kq, -0x1.921FB6p+1f, x);           // pi_hi = fp32(pi), exact in fma
    r = fmaf(kq, 8.7422777e-8f, r);                   // -(pi - pi_hi)
    const float y = r * r;
    float sp = fmaf(y, -1.9841270e-4f, 8.3333333e-3f);
    sp = fmaf(y, sp, -1.6666667e-1f);
    float s = fmaf(r * y, sp, r);
    float cp = fmaf(y, 2.4801587e-5f, -1.3888889e-3f);
    cp = fmaf(y, cp, 4.1666668e-2f);
    cp = fmaf(y, cp, -0.5f);
    float c = fmaf(y, cp, 1.0f);
    s_out = __uint_as_float(__float_as_uint(s) ^ sgn);
    c_out = __uint_as_float(__float_as_uint(c) ^ sgn);
}

__global__ __launch_bounds__(BLK) void synth_gather(
    const float* __restrict__ freq,
    const float* __restrict__ amps,
    const float* __restrict__ gainp,
    const int*  __restrict__ starts,
    const int*  __restrict__ lens,
    float* __restrict__ out)
{
    __shared__ float4 s_c0[MAXC];   // {freq, start(bits), len(bits), -} (compacted)
    __shared__ float2 s_c1[MAXC];   // {sin(freq), cos(freq)} (compacted)
    __shared__ int    s_cnt;

    const int tile_lo = (int)blockIdx.x * TILE;
    const int tile_hi = tile_lo + TILE;

    // Candidate notes = contiguous range [j0, j1) in the sorted start array.
    int lo = 0, hi = NN;
    const int v0 = tile_lo - SEGL;
    while (lo < hi) { int m = (lo + hi) >> 1; if (starts[m] > v0) hi = m; else lo = m + 1; }
    const int j0 = lo;
    lo = 0; hi = NN;
    while (lo < hi) { int m = (lo + hi) >> 1; if (starts[m] >= tile_hi) hi = m; else lo = m + 1; }
    const int j1 = lo;

    // Chebyshev-U basis combination of amps, pre-scaled by 2*g*log2(e),
    // rebased for Horner-in-cos: bt_k = b_k * 2^k.
    const float a0 = amps[0], a1 = amps[1], a2 = amps[2], a3 = amps[3];
    const float a4 = amps[4], a5 = amps[5], a6 = amps[6], a7 = amps[7];
    const float kg = gainp[0] * 2.8853900817779268f;   // 2*log2(e)
    const float bt7 = kg * a7 * 128.0f;
    const float bt6 = kg * a6 * 64.0f;
    const float bt5 = kg * (a5 - 6.0f * a7) * 32.0f;
    const float bt4 = kg * (a4 - 5.0f * a6) * 16.0f;
    const float bt3 = kg * (a3 - 4.0f * a5 + 10.0f * a7) * 8.0f;
    const float bt2 = kg * (a2 - 3.0f * a4 + 6.0f * a6) * 4.0f;
    const float bt1 = kg * (a1 - 2.0f * a3 + 3.0f * a5 - 4.0f * a7) * 2.0f;
    const float bt0 = kg * (a0 - a2 + a4 - a6);

    float acc[S];
#pragma unroll
    for (int i = 0; i < S; ++i) acc[i] = 0.0f;

    const int base = tile_lo + (int)threadIdx.x * S;

    for (int jb = j0; jb < j1; jb += MAXC) {
        const int cchunk = min(j1 - jb, MAXC);
        __syncthreads();
        // One wave stages this chunk with order-preserving ballot compaction:
        // only candidates actually overlapping the tile survive (~halves trips).
        if (threadIdx.x < 64) {
            const int lane = (int)threadIdx.x;
            bool live = false;
            float fr = 0.0f; int st = 0, ln = 0;
            if (lane < cchunk) {
                const int j = jb + lane;
                fr = freq[j];
                st = starts[j];
                ln = lens[j];
                int rem = DURS - st;      // out_len = min(start+len, dur) - start
                if (rem < 0) rem = 0;
                if (ln > rem) ln = rem;
                live = (ln > 0) && (st + ln > tile_lo);
            }
            const unsigned long long bal = __ballot(live);
            const int idx = (int)__popcll(bal & ((1ull << lane) - 1ull));
            if (live) {
                float4 v;
                v.x = fr;
                v.y = __int_as_float(st);
                v.z = __int_as_float(ln);
                v.w = 0.0f;
                s_c0[idx] = v;
                // per-candidate rotation constants; fr in [0,1) < pi/2 -> raw polys
                const float y = fr * fr;
                float sp = fmaf(y, -1.9841270e-4f, 8.3333333e-3f);
                sp = fmaf(y, sp, -1.6666667e-1f);
                const float sd = fmaf(fr * y, sp, fr);
                float cp = fmaf(y, 2.4801587e-5f, -1.3888889e-3f);
                cp = fmaf(y, cp, 4.1666668e-2f);
                cp = fmaf(y, cp, -0.5f);
                const float cd = fmaf(y, cp, 1.0f);
                s_c1[idx] = make_float2(sd, cd);
            }
            if (lane == 0) s_cnt = (int)__popcll(bal);
        }
        __syncthreads();
        const int cnt = s_cnt;

        for (int c = 0; c < cnt; ++c) {
            const float4 v = s_c0[c];
            const float fr = v.x;
            const int st = __float_as_int(v.y);
            const int ln = __float_as_int(v.z);
            const int t0 = base - st;
            // this thread's run [t0, t0+S) vs valid [0, ln)
            if (t0 >= ln || t0 + (S - 1) < 0) continue;
            const float2 w = s_c1[c];
            const float sd = w.x;
            const float cd = w.y;

            // anchor phase at this thread's first sample (reference-rounded arg)
            const float ph0 = fr * (float)t0;
            float s, cc;
            sincos_mag(ph0, s, cc);

            if (t0 >= 0 && t0 + S <= ln) {
                // full-cover fast path: no per-sample validity checks
#pragma unroll
                for (int i = 0; i < S; ++i) {
                    float q = fmaf(cc, bt7, bt6);
                    q = fmaf(cc, q, bt5);
                    q = fmaf(cc, q, bt4);
                    q = fmaf(cc, q, bt3);
                    q = fmaf(cc, q, bt2);
                    q = fmaf(cc, q, bt1);
                    q = fmaf(cc, q, bt0);
                    const float e = __builtin_amdgcn_exp2f(s * q);
                    const float rc = __builtin_amdgcn_rcpf(e + 1.0f);
                    acc[i] += fmaf(-2.0f, rc, 1.0f);
                    if (i < S - 1) {                         // last step DCE'd
                        const float sn = fmaf(cc, sd, s * cd);
                        cc = fmaf(-s, sd, cc * cd);
                        s = sn;
                    }
                }
            } else {
                // boundary path: per-sample mask
#pragma unroll
                for (int i = 0; i < S; ++i) {
                    float q = fmaf(cc, bt7, bt6);
                    q = fmaf(cc, q, bt5);
                    q = fmaf(cc, q, bt4);
                    q = fmaf(cc, q, bt3);
                    q = fmaf(cc, q, bt2);
                    q = fmaf(cc, q, bt1);
                    q = fmaf(cc, q, bt0);
                    const float e = __builtin_amdgcn_exp2f(s * q);
                    const float rc = __builtin_amdgcn_rcpf(e + 1.0f);
                    const float term = fmaf(-2.0f, rc, 1.0f);
                    const bool valid = (unsigned)(t0 + i) < (unsigned)ln;
                    acc[i] += valid ? term : 0.0f;
                    if (i < S - 1) {
                        const float sn = fmaf(cc, sd, s * cd);
                        cc = fmaf(-s, sd, cc * cd);
                        s = sn;
                    }
                }
            }
        }
    }

    // coalesced writeout: one float4 per thread (consecutive 16B per lane)
    {
        float4 o;
        o.x = acc[0]; o.y = acc[1]; o.z = acc[2]; o.w = acc[3];
        *reinterpret_cast<float4*>(&out[base]) = o;
    }
}

extern "C" void kernel_launch(void* const* d_in, const int* in_sizes, int n_in,
                              void* d_out, int out_size, void* d_ws, size_t ws_size,
                              hipStream_t stream) {
    const float* freq   = (const float*)d_in[0];
    const float* amps   = (const float*)d_in[1];
    const float* gain   = (const float*)d_in[2];
    const int*   starts = (const int*)d_in[3];
    const int*   lens   = (const int*)d_in[4];
    float* out = (float*)d_out;

    const int grid = DURS / TILE;   // 4096 blocks -> 16/CU, 8 co-resident
    synth_gather<<<grid, BLK, 0, stream>>>(freq, amps, gain, starts, lens, out);
}